// Round 1
// baseline (20949.661 us; speedup 1.0000x reference)
//
#include <hip/hip_runtime.h>

// ---------------------------------------------------------------------------
// PredRNN (patched) fp32 baseline implementation.
// Structure: per cell: kconv_xhm (fused convX/convH/convM, 3x3 Cin=64),
// kgates1 (c/m update + mem concat), kconv_ol (convO split-K + convL 1x1),
// kgates2 (h update). Final: conv3x3 + sigmoid + depth-to-space into d_out.
// ---------------------------------------------------------------------------

namespace {
constexpr int  NB    = 8;     // batch
constexpr int  T     = 19;    // in_len + out_len - 1
constexpr int  INLEN = 10;
constexpr long SL    = 524288; // one (B,64,32,32) slice in floats

// workspace offsets (floats)
constexpr long OFF_XP   = 0;          // (B,10,64,32,32)  5,242,880
constexpr long OFF_OUTS = 5242880;    // (T,B,64,32,32)   9,961,472
constexpr long OFF_H    = 15204352;   // 4*SL
constexpr long OFF_C    = 17301504;   // 4*SL
constexpr long OFF_M    = 19398656;   // SL
constexpr long OFF_XC   = 19922944;   // (B,448,32,32)
constexpr long OFF_HC   = 23592960;   // (B,256,32,32)
constexpr long OFF_MC   = 25690112;   // (B,192,32,32)
constexpr long OFF_MEM  = 27262976;   // (B,128,32,32)
constexpr long OFF_PS   = 28311552;   // 4*SL  (convO split-K partials)
constexpr long OFF_LC   = 30408704;   // SL
constexpr long OFF_WXT  = 30932992;   // 4*448*576
constexpr long OFF_WHT  = 31965184;   // 4*256*576
constexpr long OFF_WMT  = 32555008;   // 4*192*576
constexpr long OFF_WOT  = 32997376;   // 4*64*1152
constexpr long OFF_WLT  = 33292288;   // 4*64*128
constexpr long OFF_WDT  = 33325056;   // 64*576
constexpr long WS_NEEDED_FLOATS = 33361920;
}

__device__ __forceinline__ float sigf(float x)     { return 1.f / (1.f + __expf(-x)); }
__device__ __forceinline__ float tanhfast(float x) { return 2.f / (1.f + __expf(-2.f * x)) - 1.f; }

__device__ __forceinline__ void fma16(float (&a)[16], float v,
                                      const float4& w0, const float4& w1,
                                      const float4& w2, const float4& w3) {
  a[0]  += v * w0.x; a[1]  += v * w0.y; a[2]  += v * w0.z; a[3]  += v * w0.w;
  a[4]  += v * w1.x; a[5]  += v * w1.y; a[6]  += v * w1.z; a[7]  += v * w1.w;
  a[8]  += v * w2.x; a[9]  += v * w2.y; a[10] += v * w2.z; a[11] += v * w2.w;
  a[12] += v * w3.x; a[13] += v * w3.y; a[14] += v * w3.z; a[15] += v * w3.w;
}

// Core conv: block = (one batch image base inb, rows blockIdx.y*16..+15, 32 couts
// at cobase). Thread = 4 consecutive cols x 16 couts. KK = 9 (3x3) or 1 (1x1).
// Loops cin in [cin0, cin0+8*nchunks) in chunks of 8 staged via LDS.
template<int KK>
__device__ __forceinline__ void conv_core(
    const float* __restrict__ inb, const float* __restrict__ wT,
    const float* __restrict__ bias, int Cout, int cobase,
    int cin0, int nchunks, bool addBias,
    float* sIn, float* sW, float (&acc)[4][16])
{
  const int tid  = threadIdx.x;
  const int cg   = tid & 1;          // co sub-group: 16*cg
  const int pg   = tid >> 1;         // 0..127
  const int lr   = pg >> 3;          // local row 0..15
  const int c0   = (pg & 7) << 2;    // col base (multiple of 4)
  const int row0 = (int)blockIdx.y * 16;

  #pragma unroll
  for (int j = 0; j < 16; ++j) {
    float bv = addBias ? bias[cobase + cg * 16 + j] : 0.f;
    acc[0][j] = bv; acc[1][j] = bv; acc[2][j] = bv; acc[3][j] = bv;
  }

  for (int cc = 0; cc < nchunks; ++cc) {
    const int cinb = cin0 + cc * 8;
    __syncthreads();
    // stage input 8 cin x 18 rows x 34 cols (zero halo)
    for (int idx = tid; idx < 8 * 18 * 34; idx += 256) {
      int ci = idx / 612; int rem = idx - ci * 612;
      int r = rem / 34;  int c = rem - r * 34;
      int gr = row0 - 1 + r; int gc = c - 1;
      float v = 0.f;
      if ((unsigned)gr < 32u && (unsigned)gc < 32u)
        v = inb[((cinb + ci) * 32 + gr) * 32 + gc];
      sIn[idx] = v;
    }
    // stage weights 8 cin x KK taps x 32 co
    for (int idx = tid; idx < 8 * KK * 32; idx += 256) {
      int ci = idx / (KK * 32); int rem = idx - ci * (KK * 32);
      int tap = rem >> 5; int co = rem & 31;
      sW[idx] = wT[((long)((cinb + ci) * KK + tap)) * Cout + cobase + co];
    }
    __syncthreads();

    #pragma unroll
    for (int ci = 0; ci < 8; ++ci) {
      if (KK == 9) {
        float xin[3][6];
        #pragma unroll
        for (int dy = 0; dy < 3; ++dy)
          #pragma unroll
          for (int k = 0; k < 6; ++k)
            xin[dy][k] = sIn[ci * 612 + (lr + dy) * 34 + c0 + k];
        #pragma unroll
        for (int tap = 0; tap < 9; ++tap) {
          const int dy = tap / 3, dx = tap - dy * 3;
          const float4* wp = (const float4*)(sW + ci * 288 + tap * 32 + cg * 16);
          float4 w0 = wp[0], w1 = wp[1], w2 = wp[2], w3 = wp[3];
          #pragma unroll
          for (int px = 0; px < 4; ++px)
            fma16(acc[px], xin[dy][px + dx], w0, w1, w2, w3);
        }
      } else {
        const float4* wp = (const float4*)(sW + ci * 32 + cg * 16);
        float4 w0 = wp[0], w1 = wp[1], w2 = wp[2], w3 = wp[3];
        #pragma unroll
        for (int px = 0; px < 4; ++px) {
          float v = sIn[ci * 612 + (lr + 1) * 34 + (c0 + 1 + px)];
          fma16(acc[px], v, w0, w1, w2, w3);
        }
      }
    }
  }
}

__device__ __forceinline__ void store_tile(float* ob, int cobase, float (&acc)[4][16]) {
  const int tid = threadIdx.x;
  const int cg  = tid & 1;
  const int pg  = tid >> 1;
  const int row = (int)blockIdx.y * 16 + (pg >> 3);
  const int c0  = (pg & 7) << 2;
  #pragma unroll
  for (int j = 0; j < 16; ++j) {
    int co = cobase + cg * 16 + j;
    *(float4*)(ob + (long)co * 1024 + row * 32 + c0) =
        make_float4(acc[0][j], acc[1][j], acc[2][j], acc[3][j]);
  }
}

// fused convX (448) / convH (256) / convM (192); grid (8, 2, 28)
__global__ __launch_bounds__(256) void kconv_xhm(
    const float* __restrict__ in0, long in0bs,
    const float* __restrict__ h, const float* __restrict__ m,
    const float* __restrict__ wxT, const float* __restrict__ whT,
    const float* __restrict__ wmT,
    const float* __restrict__ bx, const float* __restrict__ bh,
    const float* __restrict__ bm,
    float* __restrict__ xc, float* __restrict__ hc, float* __restrict__ mc)
{
  __shared__ __align__(16) float sIn[8 * 18 * 34];
  __shared__ __align__(16) float sW[8 * 9 * 32];
  const int b = blockIdx.x;
  const int z = blockIdx.z;
  const float* in; long ibs; const float* wT; const float* bias; float* out;
  int Cout, chunk;
  if (z < 14)      { in = in0; ibs = in0bs; wT = wxT; bias = bx; out = xc; Cout = 448; chunk = z; }
  else if (z < 22) { in = h;   ibs = 65536; wT = whT; bias = bh; out = hc; Cout = 256; chunk = z - 14; }
  else             { in = m;   ibs = 65536; wT = wmT; bias = bm; out = mc; Cout = 192; chunk = z - 22; }
  float acc[4][16];
  conv_core<9>(in + (long)b * ibs, wT, bias, Cout, chunk * 32, 0, 8, true, sIn, sW, acc);
  store_tile(out + (long)b * Cout * 1024, chunk * 32, acc);
}

// convO (3x3, Cin=128, split-K into 4 partials) + convL (1x1); grid (8, 2, 10)
__global__ __launch_bounds__(256) void kconv_ol(
    const float* __restrict__ mem,
    const float* __restrict__ woT, const float* __restrict__ wlT,
    const float* __restrict__ bo, const float* __restrict__ bl,
    float* __restrict__ psum, float* __restrict__ lc)
{
  __shared__ __align__(16) float sIn[8 * 18 * 34];
  __shared__ __align__(16) float sW[8 * 9 * 32];
  const int b = blockIdx.x, z = blockIdx.z;
  const float* inb = mem + (long)b * 131072;
  float acc[4][16];
  if (z < 8) {
    int coq = z & 1, cinq = z >> 1;
    conv_core<9>(inb, woT, bo, 64, coq * 32, cinq * 32, 4, cinq == 0, sIn, sW, acc);
    store_tile(psum + (long)cinq * SL + (long)b * 65536, coq * 32, acc);
  } else {
    int coq = z - 8;
    conv_core<1>(inb, wlT, bl, 64, coq * 32, 0, 16, true, sIn, sW, acc);
    store_tile(lc + (long)b * 65536, coq * 32, acc);
  }
}

// final conv + sigmoid + depth-to-space scatter; grid (152, 2, 2)
__global__ __launch_bounds__(256) void kconv_final(
    const float* __restrict__ outs, const float* __restrict__ wdT,
    const float* __restrict__ bd, float* __restrict__ dout)
{
  __shared__ __align__(16) float sIn[8 * 18 * 34];
  __shared__ __align__(16) float sW[8 * 9 * 32];
  const int img = blockIdx.x;              // b*19 + t
  const int b = img / 19, t = img - b * 19;
  const float* inb = outs + ((long)t * NB + b) * 65536;
  float acc[4][16];
  const int coq = blockIdx.z;
  conv_core<9>(inb, wdT, bd, 64, coq * 32, 0, 8, true, sIn, sW, acc);
  const int tid = threadIdx.x;
  const int cg = tid & 1; const int pg = tid >> 1;
  const int row = (int)blockIdx.y * 16 + (pg >> 3);
  const int c0 = (pg & 7) << 2;
  float* ob = dout + (long)img * 65536;
  #pragma unroll
  for (int j = 0; j < 16; ++j) {
    int co = coq * 32 + cg * 16 + j;
    float4 v = make_float4(sigf(acc[0][j]), sigf(acc[1][j]),
                           sigf(acc[2][j]), sigf(acc[3][j]));
    *(float4*)(ob + ((co >> 3) * 32 + row) * 256 + (co & 7) * 32 + c0) = v;
  }
}

// gates: c_new, m_new, mem concat. one float4 per thread over (B,64,32,32)
__global__ __launch_bounds__(256) void kgates1(
    const float* __restrict__ xc, const float* __restrict__ hc,
    const float* __restrict__ mc,
    float* __restrict__ c, float* __restrict__ m, float* __restrict__ mem)
{
  int idx = blockIdx.x * 256 + threadIdx.x;   // 0..131071
  long e = (long)idx << 2;
  int b = (int)(e >> 16);
  int chpix = (int)(e & 65535);
  const float* xb = xc + (long)b * 458752 + chpix;
  const float* hb = hc + (long)b * 262144 + chpix;
  const float* mb = mc + (long)b * 196608 + chpix;
  float* cp = c + (long)b * 65536 + chpix;
  float* mp = m + (long)b * 65536 + chpix;
  float* memb = mem + (long)b * 131072 + chpix;
  float4 ix  = *(const float4*)xb;
  float4 fx  = *(const float4*)(xb + 65536);
  float4 gx  = *(const float4*)(xb + 131072);
  float4 ixp = *(const float4*)(xb + 196608);
  float4 fxp = *(const float4*)(xb + 262144);
  float4 gxp = *(const float4*)(xb + 327680);
  float4 ih  = *(const float4*)hb;
  float4 fh  = *(const float4*)(hb + 65536);
  float4 gh  = *(const float4*)(hb + 131072);
  float4 im  = *(const float4*)mb;
  float4 fm  = *(const float4*)(mb + 65536);
  float4 gm  = *(const float4*)(mb + 131072);
  float4 cv  = *(const float4*)cp;
  float4 mv  = *(const float4*)mp;
  float4 cn, mn;
#define G1(X) { float it = sigf(ix.X + ih.X); float ft = sigf(fx.X + fh.X);   \
                float gt = tanhfast(gx.X + gh.X);                             \
                cn.X = ft * cv.X + it * gt;                                   \
                float itp = sigf(ixp.X + im.X); float ftp = sigf(fxp.X + fm.X); \
                float gtp = tanhfast(gxp.X + gm.X);                           \
                mn.X = ftp * mv.X + itp * gtp; }
  G1(x) G1(y) G1(z) G1(w)
#undef G1
  *(float4*)cp = cn;
  *(float4*)mp = mn;
  *(float4*)memb = cn;
  *(float4*)(memb + 65536) = mn;
}

// gates: h_new = sigmoid(ox+oh+convO)*tanh(convL)
__global__ __launch_bounds__(256) void kgates2(
    const float* __restrict__ xc, const float* __restrict__ hc,
    const float* __restrict__ psum, const float* __restrict__ lc,
    float* __restrict__ h, float* __restrict__ outs_t, int writeOuts)
{
  int idx = blockIdx.x * 256 + threadIdx.x;
  long e = (long)idx << 2;
  int b = (int)(e >> 16);
  int chpix = (int)(e & 65535);
  float4 ox = *(const float4*)(xc + (long)b * 458752 + 393216 + chpix);
  float4 oh = *(const float4*)(hc + (long)b * 262144 + 196608 + chpix);
  const float* pb = psum + (long)b * 65536 + chpix;
  float4 p0 = *(const float4*)pb;
  float4 p1 = *(const float4*)(pb + SL);
  float4 p2 = *(const float4*)(pb + 2 * SL);
  float4 p3 = *(const float4*)(pb + 3 * SL);
  float4 lv = *(const float4*)(lc + (long)b * 65536 + chpix);
  float4 hv;
#define G2(X) { float o = sigf(ox.X + oh.X + p0.X + p1.X + p2.X + p3.X);      \
                hv.X = o * tanhfast(lv.X); }
  G2(x) G2(y) G2(z) G2(w)
#undef G2
  *(float4*)(h + (long)b * 65536 + chpix) = hv;
  if (writeOuts)
    *(float4*)(outs_t + (long)b * 65536 + chpix) = hv;
}

// patch division: x (B,10,1,256,256) -> xp (B,10,64,32,32)
__global__ __launch_bounds__(256) void kpatch(const float* __restrict__ x,
                                              float* __restrict__ xp)
{
  int idx = blockIdx.x * 256 + threadIdx.x;   // 1,310,720 float4s
  long e = (long)idx << 2;
  int bl = (int)(e >> 16);            // b*10 + l
  int r = (int)(e & 65535);           // ch*1024 + p*32 + q
  int ch = r >> 10; int p = (r >> 5) & 31; int q = r & 31;
  const float* src = x + (long)bl * 65536 + ((ch >> 3) * 32 + p) * 256 + (ch & 7) * 32 + q;
  *(float4*)(xp + e) = *(const float4*)src;
}

// weight transpose: src (Cout, CK) -> dst (CK, Cout)
__global__ __launch_bounds__(256) void ktransw(const float* __restrict__ src,
                                               float* __restrict__ dst,
                                               int Cout, int CK)
{
  long n = (long)Cout * CK;
  long idx = (long)blockIdx.x * 256 + threadIdx.x;
  if (idx >= n) return;
  int co = (int)(idx / CK); int ck = (int)(idx - (long)co * CK);
  dst[(long)ck * Cout + co] = src[idx];
}

extern "C" void kernel_launch(void* const* d_in, const int* in_sizes, int n_in,
                              void* d_out, int out_size, void* d_ws, size_t ws_size,
                              hipStream_t stream)
{
  (void)in_sizes; (void)n_in; (void)out_size;
  if (ws_size < WS_NEEDED_FLOATS * sizeof(float)) return;  // need ~134 MB

  const float* x  = (const float*)d_in[0];
  const float* Wx = (const float*)d_in[3];
  const float* bx = (const float*)d_in[4];
  const float* Wh = (const float*)d_in[5];
  const float* bh = (const float*)d_in[6];
  const float* Wm = (const float*)d_in[7];
  const float* bm = (const float*)d_in[8];
  const float* Wo = (const float*)d_in[9];
  const float* bo = (const float*)d_in[10];
  const float* Wl = (const float*)d_in[11];
  const float* bl = (const float*)d_in[12];
  const float* Wd = (const float*)d_in[13];
  const float* bd = (const float*)d_in[14];
  float* ws  = (float*)d_ws;
  float* out = (float*)d_out;

  // weight transposes to [cin*tap][co]
  for (int l = 0; l < 4; ++l) {
    ktransw<<<dim3((448 * 576 + 255) / 256), 256, 0, stream>>>(
        Wx + (long)l * 448 * 576, ws + OFF_WXT + (long)l * 448 * 576, 448, 576);
    ktransw<<<dim3((256 * 576 + 255) / 256), 256, 0, stream>>>(
        Wh + (long)l * 256 * 576, ws + OFF_WHT + (long)l * 256 * 576, 256, 576);
    ktransw<<<dim3((192 * 576 + 255) / 256), 256, 0, stream>>>(
        Wm + (long)l * 192 * 576, ws + OFF_WMT + (long)l * 192 * 576, 192, 576);
    ktransw<<<dim3((64 * 1152 + 255) / 256), 256, 0, stream>>>(
        Wo + (long)l * 64 * 1152, ws + OFF_WOT + (long)l * 64 * 1152, 64, 1152);
    ktransw<<<dim3((64 * 128 + 255) / 256), 256, 0, stream>>>(
        Wl + (long)l * 64 * 128, ws + OFF_WLT + (long)l * 64 * 128, 64, 128);
  }
  ktransw<<<dim3((64 * 576 + 255) / 256), 256, 0, stream>>>(Wd, ws + OFF_WDT, 64, 576);

  kpatch<<<dim3(5120), 256, 0, stream>>>(x, ws + OFF_XP);
  hipMemsetAsync(ws + OFF_H, 0, 9 * SL * sizeof(float), stream);  // h[4], c[4], m

  for (int t = 0; t < T; ++t) {
    for (int l = 0; l < 4; ++l) {
      const float* in0; long ibs;
      if (l == 0) {
        if (t < INLEN) { in0 = ws + OFF_XP + (long)t * 65536; ibs = 655360; }
        else           { in0 = ws + OFF_OUTS + (long)(t - 1) * SL; ibs = 65536; }
      } else {
        in0 = ws + OFF_H + (long)(l - 1) * SL; ibs = 65536;
      }
      kconv_xhm<<<dim3(8, 2, 28), 256, 0, stream>>>(
          in0, ibs, ws + OFF_H + (long)l * SL, ws + OFF_M,
          ws + OFF_WXT + (long)l * 448 * 576,
          ws + OFF_WHT + (long)l * 256 * 576,
          ws + OFF_WMT + (long)l * 192 * 576,
          bx + l * 448, bh + l * 256, bm + l * 192,
          ws + OFF_XC, ws + OFF_HC, ws + OFF_MC);
      kgates1<<<dim3(512), 256, 0, stream>>>(
          ws + OFF_XC, ws + OFF_HC, ws + OFF_MC,
          ws + OFF_C + (long)l * SL, ws + OFF_M, ws + OFF_MEM);
      kconv_ol<<<dim3(8, 2, 10), 256, 0, stream>>>(
          ws + OFF_MEM,
          ws + OFF_WOT + (long)l * 64 * 1152,
          ws + OFF_WLT + (long)l * 64 * 128,
          bo + l * 64, bl + l * 64, ws + OFF_PS, ws + OFF_LC);
      kgates2<<<dim3(512), 256, 0, stream>>>(
          ws + OFF_XC, ws + OFF_HC, ws + OFF_PS, ws + OFF_LC,
          ws + OFF_H + (long)l * SL, ws + OFF_OUTS + (long)t * SL,
          (l == 3) ? 1 : 0);
    }
  }
  kconv_final<<<dim3(152, 2, 2), 256, 0, stream>>>(ws + OFF_OUTS, ws + OFF_WDT, bd, out);
}

// Round 2
// 4264.064 us; speedup vs baseline: 4.9131x; 4.9131x over previous
//
#include <hip/hip_runtime.h>
#include <hip/hip_bf16.h>

// ---------------------------------------------------------------------------
// PredRNN (patched) — bf16 MFMA implicit-GEMM convs, fp32 gate math.
// conv = GEMM: M=Cout, N=pixels, K=Cin*taps via mfma_f32_16x16x32_bf16.
// Wave tile 64co x 64pix (4x4 fragments). Inputs channels-last bf16 in LDS
// (XOR-swizzled 16B slots); weights pre-packed fragment-order, global-direct.
// ---------------------------------------------------------------------------

typedef __bf16 bf16x8 __attribute__((ext_vector_type(8)));
typedef float f32x4 __attribute__((ext_vector_type(4)));

namespace {
constexpr int  T     = 19;
constexpr int  INLEN = 10;

// workspace offsets (in floats)
constexpr long OFF_XPB  = 0;           // xp bf16 [8][10][1024][64]
constexpr long OFF_OUTSB= 2621440;     // outs bf16 [19][8][1024][64]
constexpr long OFF_C    = 7602176;     // c fp32 [4][8][64][1024]
constexpr long OFF_M    = 9699328;     // m fp32 [8][64][1024]
constexpr long OFF_HB   = 10223616;    // h bf16 [4][8][1024][64]
constexpr long OFF_MB   = 11272192;    // m bf16 [8][1024][64]
constexpr long OFF_MEMB = 11534336;    // mem bf16 [8][1024][128]
constexpr long OFF_XC   = 12058624;    // xc fp32 [8][448][1024]
constexpr long OFF_HC   = 15728640;    // hc fp32 [8][256][1024]
constexpr long OFF_MC   = 17825792;    // mc fp32 [8][192][1024]
constexpr long OFF_PS   = 19398656;    // 2 x [8][64][1024]
constexpr long OFF_LC   = 20447232;    // [8][64][1024]
constexpr long OFF_WXF  = 20971520;    // frag bf16 weights
constexpr long OFF_WHF  = 21487616;
constexpr long OFF_WMF  = 21782528;
constexpr long OFF_WOF  = 22003712;
constexpr long OFF_WLF  = 22151168;
constexpr long OFF_WDF  = 22167552;
constexpr long WS_NEEDED_FLOATS = 22185984;
}

__device__ __forceinline__ float sigf(float x)     { return 1.f / (1.f + __expf(-x)); }
__device__ __forceinline__ float tanhfast(float x) { return 2.f / (1.f + __expf(-2.f * x)) - 1.f; }
__device__ __forceinline__ unsigned short f2b(float f) {
  __hip_bfloat16 h = __float2bfloat16(f);
  return __builtin_bit_cast(unsigned short, h);
}
__device__ __forceinline__ f32x4 mfma16(bf16x8 a, bf16x8 b, f32x4 c) {
  return __builtin_amdgcn_mfma_f32_16x16x32_bf16(a, b, c, 0, 0, 0);
}

// ---------------------------------------------------------------------------
// conv3x3 core: stages 64 ci (window ciOff..ciOff+63) of a 10x34 halo tile,
// K-loop 9 taps x 2 ci-chunks; A-frags global-direct from fragment-packed wf.
// Block: 8 output rows (blockIdx.y*8), 32 cols, 64 couts. 4 waves x (2 rows).
// ---------------------------------------------------------------------------
__device__ __forceinline__ void conv3_acc(
    const unsigned short* __restrict__ ip, int ciStride, int ciOff,
    const unsigned short* __restrict__ wf, int ncc, int ccoff,
    unsigned short* sIn, f32x4 (&acc)[4][4])
{
  const int tid = threadIdx.x;
  const int r0  = (int)blockIdx.y * 8;

  for (int s = tid; s < 2720; s += 256) {            // 340 slots x 8 ci-groups
    int slot = s >> 3, cg = s & 7;
    int rr = slot / 34, cl = slot - rr * 34;
    int gr = r0 - 1 + rr, gc = cl - 1;
    uint4 v = make_uint4(0u, 0u, 0u, 0u);
    if ((unsigned)gr < 32u && (unsigned)gc < 32u)
      v = *(const uint4*)(ip + (long)(gr * 32 + gc) * ciStride + ciOff + cg * 8);
    *(uint4*)(sIn + slot * 64 + ((cg ^ (slot & 7)) * 8)) = v;
  }
  __syncthreads();

  const int lane = tid & 63, w = tid >> 6;
  const int q = lane >> 4, n16 = lane & 15;

  #pragma unroll
  for (int i = 0; i < 4; ++i)
    #pragma unroll
    for (int j = 0; j < 4; ++j)
      acc[i][j] = (f32x4){0.f, 0.f, 0.f, 0.f};

  #pragma unroll
  for (int tap = 0; tap < 9; ++tap) {
    const int dy = tap / 3, dx = tap - dy * 3;       // 0..2 (lds row = orow+dy)
    #pragma unroll
    for (int cc = 0; cc < 2; ++cc) {
      const unsigned short* wp = wf + (long)(tap * ncc + ccoff + cc) * 2048 + lane * 8;
      bf16x8 a0 = *(const bf16x8*)(wp);
      bf16x8 a1 = *(const bf16x8*)(wp + 512);
      bf16x8 a2 = *(const bf16x8*)(wp + 1024);
      bf16x8 a3 = *(const bf16x8*)(wp + 1536);
      const int cs = cc * 4 + q;
      bf16x8 bfr[4];
      #pragma unroll
      for (int pf = 0; pf < 4; ++pf) {
        int slot = (w * 2 + (pf >> 1) + dy) * 34 + (pf & 1) * 16 + dx + n16;
        bfr[pf] = *(const bf16x8*)(sIn + slot * 64 + ((cs ^ (slot & 7)) * 8));
      }
      #pragma unroll
      for (int j = 0; j < 4; ++j) {
        acc[0][j] = mfma16(a0, bfr[j], acc[0][j]);
        acc[1][j] = mfma16(a1, bfr[j], acc[1][j]);
        acc[2][j] = mfma16(a2, bfr[j], acc[2][j]);
        acc[3][j] = mfma16(a3, bfr[j], acc[3][j]);
      }
    }
  }
}

__device__ __forceinline__ void conv_store(float* __restrict__ outp,
                                           const float* __restrict__ bias,
                                           f32x4 (&acc)[4][4])
{
  const int tid = threadIdx.x;
  const int lane = tid & 63, w = tid >> 6;
  const int q = lane >> 4, n16 = lane & 15;
  const int r0 = (int)blockIdx.y * 8;
  #pragma unroll
  for (int i = 0; i < 4; ++i) {
    #pragma unroll
    for (int r = 0; r < 4; ++r) {
      const int co = i * 16 + q * 4 + r;
      const float bv = bias ? bias[co] : 0.f;
      float* op = outp + (long)co * 1024 + (r0 + w * 2) * 32 + n16;
      #pragma unroll
      for (int j = 0; j < 4; ++j)
        op[(j >> 1) * 32 + (j & 1) * 16] = acc[i][j][r] + bv;
    }
  }
}

// fused convX/convH/convM; grid (8, 4, 14)
__global__ __launch_bounds__(256) void kconv_xhm(
    const unsigned short* __restrict__ in0, long in0bs,
    const unsigned short* __restrict__ hB, const unsigned short* __restrict__ mB,
    const unsigned short* __restrict__ wxf, const unsigned short* __restrict__ whf,
    const unsigned short* __restrict__ wmf,
    const float* __restrict__ bx, const float* __restrict__ bh,
    const float* __restrict__ bm,
    float* __restrict__ xc, float* __restrict__ hc, float* __restrict__ mc)
{
  __shared__ __align__(16) unsigned short sIn[21760];
  const int b = blockIdx.x, z = blockIdx.z;
  const unsigned short* in; const unsigned short* wf; const float* bias; float* out;
  if (z < 7)       { in = in0 + (long)b * in0bs; wf = wxf + (long)z * 36864;
                     bias = bx + z * 64; out = xc + (long)b * 458752 + (long)z * 65536; }
  else if (z < 11) { int k = z - 7; in = hB + (long)b * 65536; wf = whf + (long)k * 36864;
                     bias = bh + k * 64; out = hc + (long)b * 262144 + (long)k * 65536; }
  else             { int k = z - 11; in = mB + (long)b * 65536; wf = wmf + (long)k * 36864;
                     bias = bm + k * 64; out = mc + (long)b * 196608 + (long)k * 65536; }
  f32x4 acc[4][4];
  conv3_acc(in, 64, 0, wf, 2, 0, sIn, acc);
  conv_store(out, bias, acc);
}

// convO (two cin-halves -> ps0/ps1) + convL (1x1, global-direct B); grid (8,4,3)
__global__ __launch_bounds__(256) void kconv_ol(
    const unsigned short* __restrict__ memB,
    const unsigned short* __restrict__ wof, const unsigned short* __restrict__ wlf,
    const float* __restrict__ bo, const float* __restrict__ bl,
    float* __restrict__ ps, float* __restrict__ lc)
{
  __shared__ __align__(16) unsigned short sIn[21760];
  const int b = blockIdx.x, z = blockIdx.z;
  const unsigned short* ib = memB + (long)b * 131072;
  f32x4 acc[4][4];
  if (z < 2) {
    conv3_acc(ib, 128, z * 64, wof, 4, z * 2, sIn, acc);
    conv_store(ps + (long)z * 524288 + (long)b * 65536, z == 0 ? bo : nullptr, acc);
  } else {
    const int tid = threadIdx.x;
    const int lane = tid & 63, w = tid >> 6;
    const int q = lane >> 4, n16 = lane & 15;
    const int r0 = (int)blockIdx.y * 8;
    #pragma unroll
    for (int i = 0; i < 4; ++i)
      #pragma unroll
      for (int j = 0; j < 4; ++j)
        acc[i][j] = (f32x4){0.f, 0.f, 0.f, 0.f};
    #pragma unroll
    for (int cc = 0; cc < 4; ++cc) {
      const unsigned short* wp = wlf + (long)cc * 2048 + lane * 8;
      bf16x8 a0 = *(const bf16x8*)(wp);
      bf16x8 a1 = *(const bf16x8*)(wp + 512);
      bf16x8 a2 = *(const bf16x8*)(wp + 1024);
      bf16x8 a3 = *(const bf16x8*)(wp + 1536);
      bf16x8 bfr[4];
      #pragma unroll
      for (int pf = 0; pf < 4; ++pf) {
        int pix = (r0 + w * 2 + (pf >> 1)) * 32 + (pf & 1) * 16 + n16;
        bfr[pf] = *(const bf16x8*)(ib + (long)pix * 128 + cc * 32 + q * 8);
      }
      #pragma unroll
      for (int j = 0; j < 4; ++j) {
        acc[0][j] = mfma16(a0, bfr[j], acc[0][j]);
        acc[1][j] = mfma16(a1, bfr[j], acc[1][j]);
        acc[2][j] = mfma16(a2, bfr[j], acc[2][j]);
        acc[3][j] = mfma16(a3, bfr[j], acc[3][j]);
      }
    }
    conv_store(lc + (long)b * 65536, bl, acc);
  }
}

// final conv + sigmoid + depth-to-space; grid (152, 4)
__global__ __launch_bounds__(256) void kconv_final(
    const unsigned short* __restrict__ outsB,
    const unsigned short* __restrict__ wdf, const float* __restrict__ bd,
    float* __restrict__ dout)
{
  __shared__ __align__(16) unsigned short sIn[21760];
  const int img = blockIdx.x;                 // b*19 + t
  const int b = img / 19, t = img - b * 19;
  f32x4 acc[4][4];
  conv3_acc(outsB + ((long)t * 8 + b) * 65536, 64, 0, wdf, 2, 0, sIn, acc);
  const int tid = threadIdx.x;
  const int lane = tid & 63, w = tid >> 6;
  const int q = lane >> 4, n16 = lane & 15;
  const int r0 = (int)blockIdx.y * 8;
  float* ob = dout + (long)img * 65536;
  #pragma unroll
  for (int i = 0; i < 4; ++i) {
    #pragma unroll
    for (int r = 0; r < 4; ++r) {
      const int co = i * 16 + q * 4 + r;
      const float bv = bd[co];
      #pragma unroll
      for (int j = 0; j < 4; ++j) {
        int row = r0 + w * 2 + (j >> 1);
        int col = (j & 1) * 16 + n16;
        ob[((co >> 3) * 32 + row) * 256 + (co & 7) * 32 + col] = sigf(acc[i][j][r] + bv);
      }
    }
  }
}

// gates1: c/m update (fp32) + bf16 channels-last m and mem; grid (8, 8)
__global__ __launch_bounds__(256) void kgates1(
    const float* __restrict__ xc, const float* __restrict__ hc,
    const float* __restrict__ mc,
    float* __restrict__ c, float* __restrict__ m,
    unsigned short* __restrict__ mB, unsigned short* __restrict__ memB)
{
  __shared__ __align__(16) unsigned short sC[8192];
  __shared__ __align__(16) unsigned short sM[8192];
  const int b = blockIdx.x, pb0 = (int)blockIdx.y * 128, tid = threadIdx.x;
  const float* xb = xc + (long)b * 458752 + pb0;
  const float* hb = hc + (long)b * 262144 + pb0;
  const float* mcb = mc + (long)b * 196608 + pb0;
  float* cp = c + (long)b * 65536 + pb0;
  float* mp = m + (long)b * 65536 + pb0;
  for (int k = 0; k < 8; ++k) {
    int task = tid + k * 256;
    int ci = task >> 5, po = (task & 31) * 4;
    long cio = (long)ci * 1024 + po;
    float4 ix  = *(const float4*)(xb + cio);
    float4 fx  = *(const float4*)(xb + 65536 + cio);
    float4 gx  = *(const float4*)(xb + 131072 + cio);
    float4 ixp = *(const float4*)(xb + 196608 + cio);
    float4 fxp = *(const float4*)(xb + 262144 + cio);
    float4 gxp = *(const float4*)(xb + 327680 + cio);
    float4 ih  = *(const float4*)(hb + cio);
    float4 fh  = *(const float4*)(hb + 65536 + cio);
    float4 gh  = *(const float4*)(hb + 131072 + cio);
    float4 im  = *(const float4*)(mcb + cio);
    float4 fm  = *(const float4*)(mcb + 65536 + cio);
    float4 gm  = *(const float4*)(mcb + 131072 + cio);
    float4 cv  = *(const float4*)(cp + cio);
    float4 mv  = *(const float4*)(mp + cio);
    float cn[4], mn[4];
#define G1(K, X) { float it = sigf(ix.X + ih.X); float ft = sigf(fx.X + fh.X);        \
                   float gt = tanhfast(gx.X + gh.X);                                  \
                   cn[K] = ft * cv.X + it * gt;                                       \
                   float i2 = sigf(ixp.X + im.X); float f2 = sigf(fxp.X + fm.X);      \
                   float g2 = tanhfast(gxp.X + gm.X);                                 \
                   mn[K] = f2 * mv.X + i2 * g2; }
    G1(0, x) G1(1, y) G1(2, z) G1(3, w)
#undef G1
    *(float4*)(cp + cio) = make_float4(cn[0], cn[1], cn[2], cn[3]);
    *(float4*)(mp + cio) = make_float4(mn[0], mn[1], mn[2], mn[3]);
    #pragma unroll
    for (int kk = 0; kk < 4; ++kk) {
      int pix = po + kk;
      int a = pix * 64 + (((ci >> 3) ^ (pix & 7)) * 8) + (ci & 7);
      sC[a] = f2b(cn[kk]);
      sM[a] = f2b(mn[kk]);
    }
  }
  __syncthreads();
  unsigned short* mBb = mB + ((long)b * 1024 + pb0) * 64;
  unsigned short* memBb = memB + ((long)b * 1024 + pb0) * 128;
  for (int k = 0; k < 4; ++k) {
    int task = tid + k * 256;
    int pix = task >> 3, cg = task & 7;
    uint4 v = *(const uint4*)(sM + pix * 64 + ((cg ^ (pix & 7)) * 8));
    *(uint4*)(mBb + (long)pix * 64 + cg * 8) = v;
  }
  for (int k = 0; k < 8; ++k) {
    int task = tid + k * 256;
    int pix = task >> 4, cg = task & 15;
    const unsigned short* s = (cg < 8) ? sC : sM;
    int cgl = cg & 7;
    uint4 v = *(const uint4*)(s + pix * 64 + ((cgl ^ (pix & 7)) * 8));
    *(uint4*)(memBb + (long)pix * 128 + cg * 8) = v;
  }
}

// gates2: h = sig(ox+oh+convO)*tanh(convL) -> bf16 channels-last; grid (8, 8)
__global__ __launch_bounds__(256) void kgates2(
    const float* __restrict__ xc, const float* __restrict__ hc,
    const float* __restrict__ ps, const float* __restrict__ lc,
    unsigned short* __restrict__ hBl, unsigned short* __restrict__ outsBt,
    int writeOuts)
{
  __shared__ __align__(16) unsigned short sH[8192];
  const int b = blockIdx.x, pb0 = (int)blockIdx.y * 128, tid = threadIdx.x;
  for (int k = 0; k < 8; ++k) {
    int task = tid + k * 256;
    int ci = task >> 5, po = (task & 31) * 4;
    long cio = (long)ci * 1024 + pb0 + po;
    float4 ox = *(const float4*)(xc + (long)b * 458752 + 393216 + cio);
    float4 oh = *(const float4*)(hc + (long)b * 262144 + 196608 + cio);
    float4 p0 = *(const float4*)(ps + (long)b * 65536 + cio);
    float4 p1 = *(const float4*)(ps + 524288 + (long)b * 65536 + cio);
    float4 lv = *(const float4*)(lc + (long)b * 65536 + cio);
    float hv[4];
#define G2(K, X) { float o = sigf(ox.X + oh.X + p0.X + p1.X); hv[K] = o * tanhfast(lv.X); }
    G2(0, x) G2(1, y) G2(2, z) G2(3, w)
#undef G2
    #pragma unroll
    for (int kk = 0; kk < 4; ++kk) {
      int pix = po + kk;
      sH[pix * 64 + (((ci >> 3) ^ (pix & 7)) * 8) + (ci & 7)] = f2b(hv[kk]);
    }
  }
  __syncthreads();
  unsigned short* hb = hBl + ((long)b * 1024 + pb0) * 64;
  unsigned short* ob = outsBt + ((long)b * 1024 + pb0) * 64;
  for (int k = 0; k < 4; ++k) {
    int task = tid + k * 256;
    int pix = task >> 3, cg = task & 7;
    uint4 v = *(const uint4*)(sH + pix * 64 + ((cg ^ (pix & 7)) * 8));
    *(uint4*)(hb + (long)pix * 64 + cg * 8) = v;
    if (writeOuts) *(uint4*)(ob + (long)pix * 64 + cg * 8) = v;
  }
}

// patch division -> bf16 channels-last [b*10+t][1024][64]; grid (80)
__global__ __launch_bounds__(256) void kpatch(const float* __restrict__ x,
                                              unsigned short* __restrict__ xpB)
{
  __shared__ __align__(16) unsigned short sT[2048];
  const int img = blockIdx.x, tid = threadIdx.x;
  const float* xi = x + (long)img * 65536;
  unsigned short* xo = xpB + (long)img * 65536;
  for (int p = 0; p < 32; ++p) {
    __syncthreads();
    int ch = tid >> 2, q0 = (tid & 3) * 8;
    const float* s = xi + ((ch >> 3) * 32 + p) * 256 + (ch & 7) * 32 + q0;
    float4 v0 = *(const float4*)s, v1 = *(const float4*)(s + 4);
    float vv[8] = {v0.x, v0.y, v0.z, v0.w, v1.x, v1.y, v1.z, v1.w};
    #pragma unroll
    for (int k = 0; k < 8; ++k) {
      int qq = q0 + k;
      sT[qq * 64 + (((ch >> 3) ^ (qq & 7)) * 8) + (ch & 7)] = f2b(vv[k]);
    }
    __syncthreads();
    int q = tid >> 3, cg = tid & 7;
    uint4 v = *(const uint4*)(sT + q * 64 + ((cg ^ (q & 7)) * 8));
    *(uint4*)(xo + (long)(p * 32 + q) * 64 + cg * 8) = v;
  }
}

// weight fragment packing: src [Cout][Cin][KK] fp32 ->
// dst [chunk][tap][cc][cofrag][lane][8] bf16
__global__ __launch_bounds__(256) void kprepw(const float* __restrict__ src,
                                              unsigned short* __restrict__ dst,
                                              int Cout, int Cin, int KK)
{
  long n = (long)Cout * Cin * KK;
  long idx = (long)blockIdx.x * 256 + threadIdx.x;
  if (idx >= n) return;
  int ncc = Cin >> 5;
  long tmp = idx >> 3; int e = (int)(idx & 7);
  int lane = (int)(tmp & 63); tmp >>= 6;
  int cf = (int)(tmp & 3); tmp >>= 2;
  int cc = (int)(tmp % ncc); tmp /= ncc;
  int tap = (int)(tmp % KK); int chunk = (int)(tmp / KK);
  int co = chunk * 64 + cf * 16 + (lane & 15);
  int ci = cc * 32 + (lane >> 4) * 8 + e;
  dst[idx] = f2b(src[((long)co * Cin + ci) * KK + tap]);
}

extern "C" void kernel_launch(void* const* d_in, const int* in_sizes, int n_in,
                              void* d_out, int out_size, void* d_ws, size_t ws_size,
                              hipStream_t stream)
{
  (void)in_sizes; (void)n_in; (void)out_size;
  if (ws_size < WS_NEEDED_FLOATS * sizeof(float)) return;

  const float* x  = (const float*)d_in[0];
  const float* Wx = (const float*)d_in[3];
  const float* bx = (const float*)d_in[4];
  const float* Wh = (const float*)d_in[5];
  const float* bh = (const float*)d_in[6];
  const float* Wm = (const float*)d_in[7];
  const float* bm = (const float*)d_in[8];
  const float* Wo = (const float*)d_in[9];
  const float* bo = (const float*)d_in[10];
  const float* Wl = (const float*)d_in[11];
  const float* bl = (const float*)d_in[12];
  const float* Wd = (const float*)d_in[13];
  const float* bd = (const float*)d_in[14];
  float* ws  = (float*)d_ws;
  float* out = (float*)d_out;

  unsigned short* xpB   = (unsigned short*)(ws + OFF_XPB);
  unsigned short* outsB = (unsigned short*)(ws + OFF_OUTSB);
  float*          C     = ws + OFF_C;
  float*          M     = ws + OFF_M;
  unsigned short* hB    = (unsigned short*)(ws + OFF_HB);
  unsigned short* mB    = (unsigned short*)(ws + OFF_MB);
  unsigned short* memB  = (unsigned short*)(ws + OFF_MEMB);
  float*          XC    = ws + OFF_XC;
  float*          HC    = ws + OFF_HC;
  float*          MC    = ws + OFF_MC;
  float*          PS    = ws + OFF_PS;
  float*          LC    = ws + OFF_LC;
  unsigned short* wxF   = (unsigned short*)(ws + OFF_WXF);
  unsigned short* whF   = (unsigned short*)(ws + OFF_WHF);
  unsigned short* wmF   = (unsigned short*)(ws + OFF_WMF);
  unsigned short* woF   = (unsigned short*)(ws + OFF_WOF);
  unsigned short* wlF   = (unsigned short*)(ws + OFF_WLF);
  unsigned short* wdF   = (unsigned short*)(ws + OFF_WDF);

  kprepw<<<dim3(4032), 256, 0, stream>>>(Wx, wxF, 1792, 64, 9);
  kprepw<<<dim3(2304), 256, 0, stream>>>(Wh, whF, 1024, 64, 9);
  kprepw<<<dim3(1728), 256, 0, stream>>>(Wm, wmF, 768, 64, 9);
  kprepw<<<dim3(1152), 256, 0, stream>>>(Wo, woF, 256, 128, 9);
  kprepw<<<dim3(128),  256, 0, stream>>>(Wl, wlF, 256, 128, 1);
  kprepw<<<dim3(144),  256, 0, stream>>>(Wd, wdF, 64, 64, 9);
  kpatch<<<dim3(80), 256, 0, stream>>>(x, xpB);
  hipMemsetAsync(ws + OFF_C, 0, 3932160 * sizeof(float), stream);  // C,M,hB,mB

  for (int t = 0; t < T; ++t) {
    for (int l = 0; l < 4; ++l) {
      const unsigned short* in0; long ibs;
      if (l == 0) {
        if (t < INLEN) { in0 = xpB + (long)t * 65536; ibs = 655360; }
        else           { in0 = outsB + (long)(t - 1) * 524288; ibs = 65536; }
      } else {
        in0 = hB + (long)(l - 1) * 524288; ibs = 65536;
      }
      kconv_xhm<<<dim3(8, 4, 14), 256, 0, stream>>>(
          in0, ibs, hB + (long)l * 524288, mB,
          wxF + (long)l * 258048, whF + (long)l * 147456, wmF + (long)l * 110592,
          bx + l * 448, bh + l * 256, bm + l * 192, XC, HC, MC);
      kgates1<<<dim3(8, 8), 256, 0, stream>>>(
          XC, HC, MC, C + (long)l * 524288, M, mB, memB);
      kconv_ol<<<dim3(8, 4, 3), 256, 0, stream>>>(
          memB, woF + (long)l * 73728, wlF + (long)l * 8192,
          bo + l * 64, bl + l * 64, PS, LC);
      kgates2<<<dim3(8, 8), 256, 0, stream>>>(
          XC, HC, PS, LC, hB + (long)l * 524288, outsB + (long)t * 524288,
          (l == 3) ? 1 : 0);
    }
  }
  kconv_final<<<dim3(152, 4), 256, 0, stream>>>(outsB, wdF, bd, out);
}

// Round 3
// 2654.160 us; speedup vs baseline: 7.8931x; 1.6066x over previous
//
#include <hip/hip_runtime.h>
#include <hip/hip_bf16.h>

// ---------------------------------------------------------------------------
// PredRNN (patched) — fused-cell bf16 MFMA implementation.
// Per cell TWO kernels:
//  kcellA: K-concat stage-1 GEMMs ([x;h]->i,f,g,o ; [x;m]->i',f',g'),
//          7 waves = 7 gate co-tiles, LDS slab exchange, gate1 epilogue
//          (c/m update) -> writes C,M fp32, mem/m bf16 channels-last, op fp32.
//  kcellB: convO (3x3,128ci) + convL (1x1,128ci) K-split over 8 waves,
//          LDS reduce, gate2 epilogue -> h bf16 channels-last (+outs).
// Final: conv3x3 + sigmoid + depth-to-space (unchanged from R2).
// ---------------------------------------------------------------------------

typedef __bf16 bf16x8 __attribute__((ext_vector_type(8)));
typedef float f32x4 __attribute__((ext_vector_type(4)));

namespace {
constexpr int  T     = 19;
constexpr int  INLEN = 10;

// workspace offsets (in floats)
constexpr long OFF_XPB   = 0;            // bf16 [80][1024][64]
constexpr long OFF_OUTSB = 2621440;      // bf16 [19][8][1024][64]
constexpr long OFF_HB    = 7602176;      // bf16 [4][8][1024][64]
constexpr long OFF_MB    = 8650752;      // bf16 2x [8][1024][64] (ping-pong)
constexpr long OFF_C     = 9175040;      // fp32 [4][8][64][1024]
constexpr long OFF_M     = 11272192;     // fp32 [8][64][1024]
constexpr long OFF_MEMB  = 11796480;     // bf16 [8][1024][128]
constexpr long OFF_OP    = 12320768;     // fp32 [8][64][1024]
constexpr long OFF_WFA   = 12845056;     // bf16 4 x 516096
constexpr long OFF_WFB   = 13877248;     // bf16 4 x 81920
constexpr long OFF_WFD   = 14041088;     // bf16 36864
constexpr long OFF_BA    = 14059520;     // fp32 4 x 448
constexpr long WS_NEEDED_FLOATS = 14061312;
}

__device__ __forceinline__ float sigf(float x)     { return 1.f / (1.f + __expf(-x)); }
__device__ __forceinline__ float tanhfast(float x) { return 2.f / (1.f + __expf(-2.f * x)) - 1.f; }
__device__ __forceinline__ unsigned short f2b(float f) {
  __hip_bfloat16 h = __float2bfloat16(f);
  return __builtin_bit_cast(unsigned short, h);
}
__device__ __forceinline__ f32x4 mfma16(bf16x8 a, bf16x8 b, f32x4 c) {
  return __builtin_amdgcn_mfma_f32_16x16x32_bf16(a, b, c, 0, 0, 0);
}

// ---------------------------------------------------------------------------
// kcellA: grid (8 batch, 32 rows), 448 threads (7 waves).
// Wave w co-tile: w0=i w1=f w2=g w3=o (inputs x,h) ; w4=i' w5=f' w6=g' (x,m).
// ---------------------------------------------------------------------------
__global__ __launch_bounds__(448) void kcellA(
    const unsigned short* __restrict__ in0, long in0bs,
    const unsigned short* __restrict__ hB,
    const unsigned short* __restrict__ mBr,
    const unsigned short* __restrict__ wfA,
    const float* __restrict__ bA,
    float* __restrict__ C, float* __restrict__ M,
    unsigned short* __restrict__ mBw,
    unsigned short* __restrict__ memB,
    float* __restrict__ op)
{
  __shared__ __align__(16) char smem[57344];
  unsigned short* sIn = (unsigned short*)smem;   // 3 inputs x 102 slots x 64ci
  float* sEx = (float*)smem;                     // 7 slabs x 2048 fp32

  const int b = blockIdx.x, r0 = blockIdx.y, tid = threadIdx.x;
  const unsigned short* base0 = in0 + (long)b * in0bs;
  const unsigned short* base1 = hB  + (long)b * 65536;
  const unsigned short* base2 = mBr + (long)b * 65536;

  // stage 3 input row-strips (rows r0-1..r0+1, cols -1..32, 64 ci, swizzled)
  for (int s = tid; s < 3 * 816; s += 448) {
    int inp = s / 816, rem = s - inp * 816;
    int slot = rem >> 3, cg = rem & 7;
    int rr = slot / 34, cl = slot - rr * 34;
    int gr = r0 - 1 + rr, gc = cl - 1;
    const unsigned short* bp = (inp == 0) ? base0 : ((inp == 1) ? base1 : base2);
    uint4 v = make_uint4(0u, 0u, 0u, 0u);
    if ((unsigned)gr < 32u && (unsigned)gc < 32u)
      v = *(const uint4*)(bp + ((long)(gr * 32 + gc) << 6) + cg * 8);
    *(uint4*)(sIn + inp * 6528 + slot * 64 + ((cg ^ (slot & 7)) * 8)) = v;
  }
  __syncthreads();

  const int w = tid >> 6, lane = tid & 63, q = lane >> 4, n16 = lane & 15;
  f32x4 acc[4][2];
  #pragma unroll
  for (int i = 0; i < 4; ++i) { acc[i][0] = (f32x4){0,0,0,0}; acc[i][1] = (f32x4){0,0,0,0}; }

  const unsigned short* sb1 = sIn + ((w < 4) ? 6528 : 13056);
  const unsigned short* wbase = wfA + (long)w * 73728;

  #pragma unroll
  for (int p = 0; p < 2; ++p) {
    const unsigned short* sb = p ? sb1 : sIn;
    #pragma unroll
    for (int tap = 0; tap < 9; ++tap) {
      const int dy = tap / 3, dx = tap - dy * 3;
      #pragma unroll
      for (int cc = 0; cc < 2; ++cc) {
        const unsigned short* wp = wbase + (long)(((p * 9 + tap) * 2 + cc) * 4) * 512 + lane * 8;
        bf16x8 a0 = *(const bf16x8*)(wp);
        bf16x8 a1 = *(const bf16x8*)(wp + 512);
        bf16x8 a2 = *(const bf16x8*)(wp + 1024);
        bf16x8 a3 = *(const bf16x8*)(wp + 1536);
        const int g = cc * 4 + q;
        bf16x8 bf0, bf1;
        { int slot = dy * 34 + n16 + dx;
          bf0 = *(const bf16x8*)(sb + slot * 64 + ((g ^ (slot & 7)) * 8)); }
        { int slot = dy * 34 + 16 + n16 + dx;
          bf1 = *(const bf16x8*)(sb + slot * 64 + ((g ^ (slot & 7)) * 8)); }
        acc[0][0] = mfma16(a0, bf0, acc[0][0]); acc[0][1] = mfma16(a0, bf1, acc[0][1]);
        acc[1][0] = mfma16(a1, bf0, acc[1][0]); acc[1][1] = mfma16(a1, bf1, acc[1][1]);
        acc[2][0] = mfma16(a2, bf0, acc[2][0]); acc[2][1] = mfma16(a2, bf1, acc[2][1]);
        acc[3][0] = mfma16(a3, bf0, acc[3][0]); acc[3][1] = mfma16(a3, bf1, acc[3][1]);
      }
    }
  }

  __syncthreads();   // all waves done reading sIn before slab overwrite
  #pragma unroll
  for (int i = 0; i < 4; ++i)
    #pragma unroll
    for (int j = 0; j < 2; ++j)
      #pragma unroll
      for (int r = 0; r < 4; ++r)
        sEx[w * 2048 + (i * 16 + q * 4 + r) * 32 + (j * 16 + n16)] = acc[i][j][r];
  __syncthreads();

  // gate1 epilogue
  for (int idx = tid; idx < 2048; idx += 448) {
    const int ch = idx >> 5, pxl = idx & 31;
    const int pxg = r0 * 32 + pxl;
    float iv = sEx[idx]            + bA[ch];
    float fv = sEx[2048 + idx]     + bA[64 + ch];
    float gv = sEx[4096 + idx]     + bA[128 + ch];
    float ov = sEx[6144 + idx]     + bA[192 + ch];
    float i2 = sEx[8192 + idx]     + bA[256 + ch];
    float f2 = sEx[10240 + idx]    + bA[320 + ch];
    float g2 = sEx[12288 + idx]    + bA[384 + ch];
    const long cmo = ((long)b * 64 + ch) * 1024 + pxg;
    float cn = sigf(fv) * C[cmo] + sigf(iv) * tanhfast(gv);
    float mn = sigf(f2) * M[cmo] + sigf(i2) * tanhfast(g2);
    C[cmo] = cn; M[cmo] = mn; op[cmo] = ov;
    const long mo = (long)b * 1024 + pxg;
    memB[mo * 128 + ch]      = f2b(cn);
    memB[mo * 128 + 64 + ch] = f2b(mn);
    mBw[mo * 64 + ch]        = f2b(mn);
  }
}

// ---------------------------------------------------------------------------
// kcellB: grid (8, 32), 512 threads (8 waves). 40 K-steps (36 convO + 4 convL)
// split 5/wave; LDS reduce; gate2 epilogue.
// ---------------------------------------------------------------------------
__global__ __launch_bounds__(512) void kcellB(
    const unsigned short* __restrict__ memB,
    const unsigned short* __restrict__ wfB,
    const float* __restrict__ op, const float* __restrict__ bl,
    unsigned short* __restrict__ hBw, unsigned short* __restrict__ outsBt,
    int writeOuts)
{
  __shared__ __align__(16) char smem[73728];
  unsigned short* sIn = (unsigned short*)smem;   // 102 slots x 128 ci
  float* sEx = (float*)smem;                     // 9 slabs x 2048 fp32

  const int b = blockIdx.x, r0 = blockIdx.y, tid = threadIdx.x;
  const unsigned short* bp = memB + (long)b * 131072;
  for (int s = tid; s < 102 * 16; s += 512) {
    int slot = s >> 4, cg = s & 15;
    int rr = slot / 34, cl = slot - rr * 34;
    int gr = r0 - 1 + rr, gc = cl - 1;
    uint4 v = make_uint4(0u, 0u, 0u, 0u);
    if ((unsigned)gr < 32u && (unsigned)gc < 32u)
      v = *(const uint4*)(bp + ((long)(gr * 32 + gc) << 7) + cg * 8);
    *(uint4*)(sIn + slot * 128 + ((cg ^ (slot & 7)) * 8)) = v;
  }
  __syncthreads();

  const int w = tid >> 6, lane = tid & 63, q = lane >> 4, n16 = lane & 15;
  f32x4 accO[4][2], accL[4][2];
  #pragma unroll
  for (int i = 0; i < 4; ++i) {
    accO[i][0] = (f32x4){0,0,0,0}; accO[i][1] = (f32x4){0,0,0,0};
    accL[i][0] = (f32x4){0,0,0,0}; accL[i][1] = (f32x4){0,0,0,0};
  }

  #pragma unroll
  for (int s5 = 0; s5 < 5; ++s5) {
    const int s = w * 5 + s5;
    const bool isL = (s >= 36);
    const int tap = isL ? 4 : (s >> 2);
    const int cc  = isL ? (s - 36) : (s & 3);
    const int dy = tap / 3, dx = tap - dy * 3;
    const unsigned short* wp = wfB + (long)s * 2048 + lane * 8;
    bf16x8 a0 = *(const bf16x8*)(wp);
    bf16x8 a1 = *(const bf16x8*)(wp + 512);
    bf16x8 a2 = *(const bf16x8*)(wp + 1024);
    bf16x8 a3 = *(const bf16x8*)(wp + 1536);
    const int g = cc * 4 + q;
    bf16x8 bf0, bf1;
    { int slot = dy * 34 + n16 + dx;
      bf0 = *(const bf16x8*)(sIn + slot * 128 + ((g ^ (slot & 7)) * 8)); }
    { int slot = dy * 34 + 16 + n16 + dx;
      bf1 = *(const bf16x8*)(sIn + slot * 128 + ((g ^ (slot & 7)) * 8)); }
    if (isL) {
      accL[0][0] = mfma16(a0, bf0, accL[0][0]); accL[0][1] = mfma16(a0, bf1, accL[0][1]);
      accL[1][0] = mfma16(a1, bf0, accL[1][0]); accL[1][1] = mfma16(a1, bf1, accL[1][1]);
      accL[2][0] = mfma16(a2, bf0, accL[2][0]); accL[2][1] = mfma16(a2, bf1, accL[2][1]);
      accL[3][0] = mfma16(a3, bf0, accL[3][0]); accL[3][1] = mfma16(a3, bf1, accL[3][1]);
    } else {
      accO[0][0] = mfma16(a0, bf0, accO[0][0]); accO[0][1] = mfma16(a0, bf1, accO[0][1]);
      accO[1][0] = mfma16(a1, bf0, accO[1][0]); accO[1][1] = mfma16(a1, bf1, accO[1][1]);
      accO[2][0] = mfma16(a2, bf0, accO[2][0]); accO[2][1] = mfma16(a2, bf1, accO[2][1]);
      accO[3][0] = mfma16(a3, bf0, accO[3][0]); accO[3][1] = mfma16(a3, bf1, accO[3][1]);
    }
  }

  __syncthreads();
  #pragma unroll
  for (int i = 0; i < 4; ++i)
    #pragma unroll
    for (int j = 0; j < 2; ++j)
      #pragma unroll
      for (int r = 0; r < 4; ++r)
        sEx[w * 2048 + (i * 16 + q * 4 + r) * 32 + (j * 16 + n16)] = accO[i][j][r];
  if (w == 7) {
    #pragma unroll
    for (int i = 0; i < 4; ++i)
      #pragma unroll
      for (int j = 0; j < 2; ++j)
        #pragma unroll
        for (int r = 0; r < 4; ++r)
          sEx[16384 + (i * 16 + q * 4 + r) * 32 + (j * 16 + n16)] = accL[i][j][r];
  }
  __syncthreads();

  for (int idx = tid; idx < 2048; idx += 512) {
    const int ch = idx >> 5, pxl = idx & 31;
    const int pxg = r0 * 32 + pxl;
    float o = op[((long)b * 64 + ch) * 1024 + pxg];
    #pragma unroll
    for (int ww = 0; ww < 8; ++ww) o += sEx[ww * 2048 + idx];
    float l = sEx[16384 + idx] + bl[ch];
    unsigned short hv = f2b(sigf(o) * tanhfast(l));
    hBw[((long)b * 1024 + pxg) * 64 + ch] = hv;
    if (writeOuts) outsBt[((long)b * 1024 + pxg) * 64 + ch] = hv;
  }
}

// ---------------------------------------------------------------------------
// Final conv machinery (verbatim from R2, proven correct)
// ---------------------------------------------------------------------------
__device__ __forceinline__ void conv3_acc(
    const unsigned short* __restrict__ ip, int ciStride, int ciOff,
    const unsigned short* __restrict__ wf, int ncc, int ccoff,
    unsigned short* sIn, f32x4 (&acc)[4][4])
{
  const int tid = threadIdx.x;
  const int r0  = (int)blockIdx.y * 8;
  for (int s = tid; s < 2720; s += 256) {
    int slot = s >> 3, cg = s & 7;
    int rr = slot / 34, cl = slot - rr * 34;
    int gr = r0 - 1 + rr, gc = cl - 1;
    uint4 v = make_uint4(0u, 0u, 0u, 0u);
    if ((unsigned)gr < 32u && (unsigned)gc < 32u)
      v = *(const uint4*)(ip + (long)(gr * 32 + gc) * ciStride + ciOff + cg * 8);
    *(uint4*)(sIn + slot * 64 + ((cg ^ (slot & 7)) * 8)) = v;
  }
  __syncthreads();
  const int lane = tid & 63, w = tid >> 6;
  const int q = lane >> 4, n16 = lane & 15;
  #pragma unroll
  for (int i = 0; i < 4; ++i)
    #pragma unroll
    for (int j = 0; j < 4; ++j)
      acc[i][j] = (f32x4){0.f, 0.f, 0.f, 0.f};
  #pragma unroll
  for (int tap = 0; tap < 9; ++tap) {
    const int dy = tap / 3, dx = tap - dy * 3;
    #pragma unroll
    for (int cc = 0; cc < 2; ++cc) {
      const unsigned short* wp = wf + (long)(tap * ncc + ccoff + cc) * 2048 + lane * 8;
      bf16x8 a0 = *(const bf16x8*)(wp);
      bf16x8 a1 = *(const bf16x8*)(wp + 512);
      bf16x8 a2 = *(const bf16x8*)(wp + 1024);
      bf16x8 a3 = *(const bf16x8*)(wp + 1536);
      const int cs = cc * 4 + q;
      bf16x8 bfr[4];
      #pragma unroll
      for (int pf = 0; pf < 4; ++pf) {
        int slot = (w * 2 + (pf >> 1) + dy) * 34 + (pf & 1) * 16 + dx + n16;
        bfr[pf] = *(const bf16x8*)(sIn + slot * 64 + ((cs ^ (slot & 7)) * 8));
      }
      #pragma unroll
      for (int j = 0; j < 4; ++j) {
        acc[0][j] = mfma16(a0, bfr[j], acc[0][j]);
        acc[1][j] = mfma16(a1, bfr[j], acc[1][j]);
        acc[2][j] = mfma16(a2, bfr[j], acc[2][j]);
        acc[3][j] = mfma16(a3, bfr[j], acc[3][j]);
      }
    }
  }
}

__global__ __launch_bounds__(256) void kconv_final(
    const unsigned short* __restrict__ outsB,
    const unsigned short* __restrict__ wdf, const float* __restrict__ bd,
    float* __restrict__ dout)
{
  __shared__ __align__(16) unsigned short sIn[21760];
  const int img = blockIdx.x;
  const int b = img / 19, t = img - b * 19;
  f32x4 acc[4][4];
  conv3_acc(outsB + ((long)t * 8 + b) * 65536, 64, 0, wdf, 2, 0, sIn, acc);
  const int tid = threadIdx.x;
  const int lane = tid & 63, w = tid >> 6;
  const int q = lane >> 4, n16 = lane & 15;
  const int r0 = (int)blockIdx.y * 8;
  float* ob = dout + (long)img * 65536;
  #pragma unroll
  for (int i = 0; i < 4; ++i) {
    #pragma unroll
    for (int r = 0; r < 4; ++r) {
      const int co = i * 16 + q * 4 + r;
      const float bv = bd[co];
      #pragma unroll
      for (int j = 0; j < 4; ++j) {
        int row = r0 + w * 2 + (j >> 1);
        int col = (j & 1) * 16 + n16;
        ob[((co >> 3) * 32 + row) * 256 + (co & 7) * 32 + col] = sigf(acc[i][j][r] + bv);
      }
    }
  }
}

// patch division -> bf16 channels-last [b*10+t][1024][64]; grid (80)
__global__ __launch_bounds__(256) void kpatch(const float* __restrict__ x,
                                              unsigned short* __restrict__ xpB)
{
  __shared__ __align__(16) unsigned short sT[2048];
  const int img = blockIdx.x, tid = threadIdx.x;
  const float* xi = x + (long)img * 65536;
  unsigned short* xo = xpB + (long)img * 65536;
  for (int p = 0; p < 32; ++p) {
    __syncthreads();
    int ch = tid >> 2, q0 = (tid & 3) * 8;
    const float* s = xi + ((ch >> 3) * 32 + p) * 256 + (ch & 7) * 32 + q0;
    float4 v0 = *(const float4*)s, v1 = *(const float4*)(s + 4);
    float vv[8] = {v0.x, v0.y, v0.z, v0.w, v1.x, v1.y, v1.z, v1.w};
    #pragma unroll
    for (int k = 0; k < 8; ++k) {
      int qq = q0 + k;
      sT[qq * 64 + (((ch >> 3) ^ (qq & 7)) * 8) + (ch & 7)] = f2b(vv[k]);
    }
    __syncthreads();
    int q = tid >> 3, cg = tid & 7;
    uint4 v = *(const uint4*)(sT + q * 64 + ((cg ^ (q & 7)) * 8));
    *(uint4*)(xo + (long)(p * 32 + q) * 64 + cg * 8) = v;
  }
}

// R2 weight fragment packer (used for Wd only)
__global__ __launch_bounds__(256) void kprepw(const float* __restrict__ src,
                                              unsigned short* __restrict__ dst,
                                              int Cout, int Cin, int KK)
{
  long n = (long)Cout * Cin * KK;
  long idx = (long)blockIdx.x * 256 + threadIdx.x;
  if (idx >= n) return;
  int ncc = Cin >> 5;
  long tmp = idx >> 3; int e = (int)(idx & 7);
  int lane = (int)(tmp & 63); tmp >>= 6;
  int cf = (int)(tmp & 3); tmp >>= 2;
  int cc = (int)(tmp % ncc); tmp /= ncc;
  int tap = (int)(tmp % KK); int chunk = (int)(tmp / KK);
  int co = chunk * 64 + cf * 16 + (lane & 15);
  int ci = cc * 32 + (lane >> 4) * 8 + e;
  dst[idx] = f2b(src[((long)co * Cin + ci) * KK + tap]);
}

// pack fused stage-1 weights: [l][w][p][tap][cc][frag][lane][8]
__global__ __launch_bounds__(256) void kpackA(
    const float* __restrict__ Wx, const float* __restrict__ Wh,
    const float* __restrict__ Wm, unsigned short* __restrict__ wfA)
{
  long idx = (long)blockIdx.x * 256 + threadIdx.x;
  if (idx >= 2064384) return;
  int e = (int)(idx & 7);
  long t = idx >> 3;
  int lane = (int)(t & 63); t >>= 6;
  int frag = (int)(t & 3);  t >>= 2;
  int cc   = (int)(t & 1);  t >>= 1;
  int tap  = (int)(t % 9);  t /= 9;
  int p    = (int)(t & 1);  t >>= 1;
  int w    = (int)(t % 7);
  int l    = (int)(t / 7);
  int co = frag * 16 + (lane & 15);
  int ci = cc * 32 + (lane >> 4) * 8 + e;
  const float* src; int row;
  if (w < 4) {
    if (p == 0) { src = Wx + (long)l * 258048; row = (w == 3 ? 384 : w * 64) + co; }
    else        { src = Wh + (long)l * 147456; row = (w == 3 ? 192 : w * 64) + co; }
  } else {
    if (p == 0) { src = Wx + (long)l * 258048; row = 192 + (w - 4) * 64 + co; }
    else        { src = Wm + (long)l * 110592; row = (w - 4) * 64 + co; }
  }
  wfA[idx] = f2b(src[((long)row * 64 + ci) * 9 + tap]);
}

// pack convO/convL step-ordered weights: [l][s 0..39][frag][lane][8]
__global__ __launch_bounds__(256) void kpackB(
    const float* __restrict__ Wo, const float* __restrict__ Wl,
    unsigned short* __restrict__ wfB)
{
  long idx = (long)blockIdx.x * 256 + threadIdx.x;
  if (idx >= 327680) return;
  int e = (int)(idx & 7);
  long t = idx >> 3;
  int lane = (int)(t & 63); t >>= 6;
  int frag = (int)(t & 3);  t >>= 2;
  int s    = (int)(t % 40);
  int l    = (int)(t / 40);
  int co = frag * 16 + (lane & 15);
  float v;
  if (s < 36) {
    int tap = s >> 2, cc = s & 3;
    int ci = cc * 32 + (lane >> 4) * 8 + e;
    v = Wo[(long)l * 73728 + ((long)co * 128 + ci) * 9 + tap];
  } else {
    int cc = s - 36;
    int ci = cc * 32 + (lane >> 4) * 8 + e;
    v = Wl[(long)l * 8192 + (long)co * 128 + ci];
  }
  wfB[idx] = f2b(v);
}

// pre-summed gate biases: [l][w][64]
__global__ __launch_bounds__(256) void kpackbA(
    const float* __restrict__ bx, const float* __restrict__ bh,
    const float* __restrict__ bm, const float* __restrict__ bo,
    float* __restrict__ bA)
{
  int idx = blockIdx.x * 256 + threadIdx.x;
  if (idx >= 1792) return;
  int ch = idx & 63, w = (idx >> 6) % 7, l = (idx >> 6) / 7;
  const float* bxl = bx + l * 448;
  const float* bhl = bh + l * 256;
  const float* bml = bm + l * 192;
  const float* bol = bo + l * 64;
  float v;
  if (w < 3)       v = bxl[w * 64 + ch] + bhl[w * 64 + ch];
  else if (w == 3) v = bxl[384 + ch] + bhl[192 + ch] + bol[ch];
  else             v = bxl[192 + (w - 4) * 64 + ch] + bml[(w - 4) * 64 + ch];
  bA[idx] = v;
}

extern "C" void kernel_launch(void* const* d_in, const int* in_sizes, int n_in,
                              void* d_out, int out_size, void* d_ws, size_t ws_size,
                              hipStream_t stream)
{
  (void)in_sizes; (void)n_in; (void)out_size;
  if (ws_size < WS_NEEDED_FLOATS * sizeof(float)) return;

  const float* x  = (const float*)d_in[0];
  const float* Wx = (const float*)d_in[3];
  const float* bx = (const float*)d_in[4];
  const float* Wh = (const float*)d_in[5];
  const float* bh = (const float*)d_in[6];
  const float* Wm = (const float*)d_in[7];
  const float* bm = (const float*)d_in[8];
  const float* Wo = (const float*)d_in[9];
  const float* bo = (const float*)d_in[10];
  const float* Wl = (const float*)d_in[11];
  const float* bl = (const float*)d_in[12];
  const float* Wd = (const float*)d_in[13];
  const float* bd = (const float*)d_in[14];
  float* ws  = (float*)d_ws;
  float* out = (float*)d_out;

  unsigned short* xpB   = (unsigned short*)(ws + OFF_XPB);
  unsigned short* outsB = (unsigned short*)(ws + OFF_OUTSB);
  unsigned short* hB    = (unsigned short*)(ws + OFF_HB);
  unsigned short* mB0   = (unsigned short*)(ws + OFF_MB);
  unsigned short* mB1   = mB0 + 524288;
  float*          C     = ws + OFF_C;
  float*          M     = ws + OFF_M;
  unsigned short* memB  = (unsigned short*)(ws + OFF_MEMB);
  float*          OP    = ws + OFF_OP;
  unsigned short* wfA   = (unsigned short*)(ws + OFF_WFA);
  unsigned short* wfB   = (unsigned short*)(ws + OFF_WFB);
  unsigned short* wfD   = (unsigned short*)(ws + OFF_WFD);
  float*          bA    = ws + OFF_BA;

  kpackA<<<dim3(8064), 256, 0, stream>>>(Wx, Wh, Wm, wfA);
  kpackB<<<dim3(1280), 256, 0, stream>>>(Wo, Wl, wfB);
  kpackbA<<<dim3(7), 256, 0, stream>>>(bx, bh, bm, bo, bA);
  kprepw<<<dim3(144), 256, 0, stream>>>(Wd, wfD, 64, 64, 9);
  kpatch<<<dim3(80), 256, 0, stream>>>(x, xpB);
  // zero h, m(bf16 x2), C, M  (contiguous region)
  hipMemsetAsync(ws + OFF_HB, 0, (OFF_MEMB - OFF_HB) * sizeof(float), stream);

  for (int t = 0; t < T; ++t) {
    for (int l = 0; l < 4; ++l) {
      const int cell = t * 4 + l;
      const unsigned short* in0; long ibs;
      if (l == 0) {
        if (t < INLEN) { in0 = xpB + (long)t * 65536; ibs = 655360; }
        else           { in0 = outsB + (long)(t - 1) * 524288; ibs = 65536; }
      } else {
        in0 = hB + (long)(l - 1) * 524288; ibs = 65536;
      }
      const unsigned short* mBr = (cell & 1) ? mB1 : mB0;
      unsigned short*       mBw = (cell & 1) ? mB0 : mB1;
      kcellA<<<dim3(8, 32), 448, 0, stream>>>(
          in0, ibs, hB + (long)l * 524288, mBr,
          wfA + (long)l * 516096, bA + l * 448,
          C + (long)l * 524288, M, mBw, memB, OP);
      kcellB<<<dim3(8, 32), 512, 0, stream>>>(
          memB, wfB + (long)l * 81920, OP, bl + l * 64,
          hB + (long)l * 524288, outsB + (long)t * 524288, (l == 3) ? 1 : 0);
    }
  }
  kconv_final<<<dim3(152, 4), 256, 0, stream>>>(outsB, wfD, bd, out);
}